// Round 8
// baseline (862.249 us; speedup 1.0000x reference)
//
#include <hip/hip_runtime.h>
#include <math.h>

typedef __attribute__((ext_vector_type(8))) __bf16 bf16x8;
typedef __attribute__((ext_vector_type(4))) float floatx4;

#define NROW 16384
#define KCB  8192
#define TAU  0.6f           // guard threshold; K=512 score-diff err sigma~0.08 -> 7.5 sigma
#define NNB  32             // KCB / 256 n-blocks

// workspace byte offsets
#define OFF_PACKED 0u                    // 16384*8
#define OFF_A      131072u               // 16384*512*2 (zh|zl)
#define OFF_B      16908288u             // 8192*256*2 frag-swizzled eh (4.2 MB)
#define OFF_ZT     25296896u             // 16384*256*4 fp32 z transposed
#define OFF_NRM    42074112u             // 8192*4
#define OFF_PM1    42106880u             // 32*16384*4
#define OFF_PM2    44204032u
#define OFF_PIDX   46301184u
#define OFF_FIDX   48398336u             // 16384*4
#define OFF_LIST   48463872u             // 16384*4
#define OFF_FLAG   48529408u             // 16384*4
#define OFF_HIST   48594944u             // 8192*4
#define OFF_MISC   48627712u             // [0] unused, [1] cnt
#define OFF_SC1    48627728u             // 16384*4 approx min-score per row
#define OFF_ZNP    48693264u             // 1024*4 per-block ||z||^2 partials

__device__ __forceinline__ unsigned short f2bf(float f) {  // RNE fp32->bf16
  unsigned u = __float_as_uint(f);
  return (unsigned short)((u + 0x7FFFu + ((u >> 16) & 1u)) >> 16);
}
__device__ __forceinline__ float bf2f(unsigned short b) {
  return __uint_as_float(((unsigned)b) << 16);
}
__device__ __forceinline__ unsigned pack2(unsigned short a, unsigned short b) {
  return (unsigned)a | ((unsigned)b << 16);
}
__device__ __forceinline__ void gld16(const void* g, void* l) {
  __builtin_amdgcn_global_load_lds(
      (const __attribute__((address_space(1))) unsigned int*)g,
      (__attribute__((address_space(3))) unsigned int*)l, 16, 0, 0);
}
__device__ __forceinline__ float dec_sortable(unsigned u) {  // inverse of encode
  return __uint_as_float((u & 0x80000000u) ? (u ^ 0x80000000u) : ~u);
}

// ================= fused prep =================
// bid <1024:      A-prep (z transpose -> A'[n][512]=[zh|zl] + zt fp32 + znp)
// 1024..2047:     B'-prep: frag-swizzled eh, B2[((nb*8+kk)*16+ct)*512 + lane*8]
// 2048..2559:     codebook norms (16 rows/block)
// 2560..2591:     zero hist (+ misc on first)
__global__ __launch_bounds__(256) void prep_k(
    const float* __restrict__ z, const float* __restrict__ cb,
    unsigned short* __restrict__ A, unsigned short* __restrict__ B2,
    float* __restrict__ zt, float* __restrict__ nrm, int* __restrict__ hist,
    int* __restrict__ misc, float* __restrict__ znp) {
  const int tid = threadIdx.x;
  if (blockIdx.x < 1024) {
    __shared__ float t[64][65];
    __shared__ float zps[4];
    const int bb = blockIdx.x >> 6;
    const int hw0 = ((blockIdx.x >> 2) & 15) * 64;
    const int c0 = (blockIdx.x & 3) * 64;
    const int cl = tid >> 2, h4 = (tid & 3) * 16;
    const float* src = z + ((size_t)(bb * 256 + c0 + cl)) * 1024 + hw0 + h4;
#pragma unroll
    for (int j = 0; j < 4; ++j) {
      const float4 v = *(const float4*)(src + 4 * j);
      t[cl][h4 + 4 * j + 0] = v.x; t[cl][h4 + 4 * j + 1] = v.y;
      t[cl][h4 + 4 * j + 2] = v.z; t[cl][h4 + 4 * j + 3] = v.w;
    }
    __syncthreads();
    const int hl = tid >> 2, cq = (tid & 3) * 16;
    const size_t n = (size_t)bb * 1024 + hw0 + hl;
    float fv[16];
    unsigned short hi[16], lo[16];
    float part = 0.f;
#pragma unroll
    for (int j = 0; j < 16; ++j) {
      const float f = t[cq + j][hl];
      fv[j] = f;
      part += f * f;
      const unsigned short h = f2bf(f);
      hi[j] = h;
      lo[j] = f2bf(f - bf2f(h));
    }
    unsigned short* dst = A + n * 512 + c0 + cq;
    uint4 h0 = {pack2(hi[0], hi[1]), pack2(hi[2], hi[3]), pack2(hi[4], hi[5]), pack2(hi[6], hi[7])};
    uint4 h1 = {pack2(hi[8], hi[9]), pack2(hi[10], hi[11]), pack2(hi[12], hi[13]), pack2(hi[14], hi[15])};
    uint4 l0 = {pack2(lo[0], lo[1]), pack2(lo[2], lo[3]), pack2(lo[4], lo[5]), pack2(lo[6], lo[7])};
    uint4 l1 = {pack2(lo[8], lo[9]), pack2(lo[10], lo[11]), pack2(lo[12], lo[13]), pack2(lo[14], lo[15])};
    *(uint4*)(dst) = h0;        *(uint4*)(dst + 8) = h1;       // zh at [c]
    *(uint4*)(dst + 256) = l0;  *(uint4*)(dst + 264) = l1;     // zl at [256+c]
    float* zp = zt + n * 256 + c0 + cq;
#pragma unroll
    for (int j = 0; j < 4; ++j) {
      float4 v = {fv[4 * j], fv[4 * j + 1], fv[4 * j + 2], fv[4 * j + 3]};
      *(float4*)(zp + 4 * j) = v;
    }
    // block-local ||z||^2 partial (summed across all 1024 blocks in final)
    const int lane = tid & 63, wid = tid >> 6;
    for (int off = 32; off; off >>= 1) part += __shfl_down(part, off);
    if (lane == 0) zps[wid] = part;
    __syncthreads();
    if (tid == 0) znp[blockIdx.x] = zps[0] + zps[1] + zps[2] + zps[3];
  } else if (blockIdx.x < 2048) {
    // one thread per B' octet: g = ((nb*8 + kk)*16 + ct)*64 + l
    const int g = (blockIdx.x - 1024) * 256 + tid;
    const int l = g & 63;
    const int ct = (g >> 6) & 15;
    const int kk = (g >> 10) & 7;
    const int nb = g >> 13;
    const int e = nb * 256 + ct * 16 + (l & 15);
    const int c0 = kk * 32 + (l >> 4) * 8;
    const float4 v0 = *(const float4*)(cb + (size_t)e * 256 + c0);
    const float4 v1 = *(const float4*)(cb + (size_t)e * 256 + c0 + 4);
    float f[8] = {v0.x, v0.y, v0.z, v0.w, v1.x, v1.y, v1.z, v1.w};
    unsigned short o[8];
#pragma unroll
    for (int j = 0; j < 8; ++j) o[j] = f2bf(f[j]);
    uint4 w = {pack2(o[0], o[1]), pack2(o[2], o[3]), pack2(o[4], o[5]), pack2(o[6], o[7])};
    *(uint4*)(B2 + (size_t)g * 8) = w;
  } else if (blockIdx.x < 2560) {
    const int row = (blockIdx.x - 2048) * 16 + (tid >> 4);
    const int l16 = tid & 15;
    const float* cr = cb + (size_t)row * 256 + l16 * 16;
    float s = 0.f;
#pragma unroll
    for (int j = 0; j < 4; ++j) {
      const float4 v = *(const float4*)(cr + 4 * j);
      s += v.x * v.x + v.y * v.y + v.z * v.z + v.w * v.w;
    }
    s += __shfl_xor(s, 8); s += __shfl_xor(s, 4);
    s += __shfl_xor(s, 2); s += __shfl_xor(s, 1);
    if (l16 == 0) nrm[row] = s;
  } else {
    const int i = blockIdx.x - 2560;   // 0..31
    hist[i * 256 + tid] = 0;
    if (i == 0 && tid < 2) misc[tid] = 0;
  }
}

// ================= main: bf16 MFMA distance GEMM + fused top-2 argmin ========
// K=512 split ([zh|zl].[eh|eh]); A staged in LDS (16 KB, XOR-swizzle, proven
// R3-R7), B frags loaded global->VGPR from pre-swizzled B' (validated R5).
// Removing B from LDS cuts LDS traffic/chunk 144->80 KB (R7 model: LDS-bound).
// terms: kc 0-3 zh.eh | kc 4-7 zl.eh
__global__ __launch_bounds__(256, 2) void vq_mfma_k(
    const unsigned short* __restrict__ A, const unsigned short* __restrict__ B2,
    const float* __restrict__ nrm, float* __restrict__ pm1,
    float* __restrict__ pm2, int* __restrict__ pidx) {
  __shared__ unsigned short As[128 * 64];  // 16 KB

  const int tid = threadIdx.x;
  const int mb = blockIdx.y, nb = blockIdx.x;
  const int w = tid >> 6, lane = tid & 63;
  const int quad = lane >> 4, lrow = lane & 15;

  const int sr = tid >> 3, ss = tid & 7;
  const int sq = ss ^ (sr & 7);
  const unsigned short* gA = A + (size_t)(mb * 128 + sr) * 512 + sq * 8;
  unsigned short* lA = As + sr * 64 + ss * 8;
  // B' per nb: 8 kk * 16 ct * 512; wave w owns ct = w*4 + nt
  const unsigned short* bp =
      B2 + (size_t)nb * 65536 + (size_t)(w * 4) * 512 + lane * 8;

  floatx4 acc[8][4];
#pragma unroll
  for (int i = 0; i < 8; ++i)
#pragma unroll
    for (int j = 0; j < 4; ++j) acc[i][j] = (floatx4){0.f, 0.f, 0.f, 0.f};

  for (int kc = 0; kc < 8; ++kc) {
    const int koA = ((kc & 3) << 6) + ((kc >= 4) ? 256 : 0);
#pragma unroll
    for (int i = 0; i < 4; ++i)
      gld16(gA + (size_t)(i * 32) * 512 + koA, lA + i * 32 * 64);
    bf16x8 bfr[2][4];
#pragma unroll
    for (int ks = 0; ks < 2; ++ks) {
      const int phys = ((kc & 3) << 1) + ks;   // 0..7 (eh reused for zl pass)
#pragma unroll
      for (int nt = 0; nt < 4; ++nt)
        bfr[ks][nt] = *(const bf16x8*)(bp + (size_t)phys * 8192 + nt * 512);
    }
    __syncthreads();
#pragma unroll
    for (int ks = 0; ks < 2; ++ks) {
      bf16x8 af[8];
#pragma unroll
      for (int mt = 0; mt < 8; ++mt) {
        const int row = mt * 16 + lrow;
        const int slot = (ks * 4 + quad) ^ (row & 7);
        af[mt] = *(const bf16x8*)(As + row * 64 + slot * 8);
      }
#pragma unroll
      for (int mt = 0; mt < 8; ++mt)
#pragma unroll
        for (int nt = 0; nt < 4; ++nt)
          acc[mt][nt] = __builtin_amdgcn_mfma_f32_16x16x32_bf16(
              af[mt], bfr[ks][nt], acc[mt][nt], 0, 0, 0);
    }
    __syncthreads();
  }

  // ---- epilogue: score = nrm[k] - 2*dot; top-2 per row over 256 cols ----
  float nr[4];
#pragma unroll
  for (int nt = 0; nt < 4; ++nt) nr[nt] = nrm[nb * 256 + w * 64 + nt * 16 + lrow];

  float* Lm1 = (float*)As;             // overlay (As dead after loop)
  int* Li1 = (int*)(As + 2048);
  float* Lm2 = (float*)(As + 4096);
#pragma unroll
  for (int mt = 0; mt < 8; ++mt) {
#pragma unroll
    for (int p = 0; p < 4; ++p) {
      float m1 = 3e38f, m2 = 3e38f;
      int i1 = 0;
#pragma unroll
      for (int nt = 0; nt < 4; ++nt) {
        const float s = nr[nt] - 2.0f * acc[mt][nt][p];
        const int kg = nb * 256 + w * 64 + nt * 16 + lrow;
        if (s < m1) { m2 = m1; m1 = s; i1 = kg; }
        else m2 = fminf(m2, s);
      }
      for (int d = 1; d < 16; d <<= 1) {   // merge across 16 lrow lanes
        const float om1 = __shfl_xor(m1, d);
        const int oi1 = __shfl_xor(i1, d);
        const float om2 = __shfl_xor(m2, d);
        if (om1 < m1) { m2 = fminf(m1, om2); m1 = om1; i1 = oi1; }
        else          { m2 = fminf(m2, om1); }
      }
      if (lrow == 0) {
        const int rl = mt * 16 + quad * 4 + p;
        Lm1[rl * 4 + w] = m1; Li1[rl * 4 + w] = i1; Lm2[rl * 4 + w] = m2;
      }
    }
  }
  __syncthreads();
  if (tid < 128) {
    float m1 = Lm1[tid * 4], m2 = Lm2[tid * 4];
    int i1 = Li1[tid * 4];
#pragma unroll
    for (int v = 1; v < 4; ++v) {
      const float om1 = Lm1[tid * 4 + v], om2 = Lm2[tid * 4 + v];
      const int oi1 = Li1[tid * 4 + v];
      if (om1 < m1) { m2 = fminf(m1, om2); m1 = om1; i1 = oi1; }
      else          { m2 = fminf(m2, om1); }
    }
    const int r = mb * 128 + tid;
    pm1[(size_t)nb * NROW + r] = m1;
    pm2[(size_t)nb * NROW + r] = m2;
    pidx[(size_t)nb * NROW + r] = i1;
  }
}

// ================= reduce partials + provisional finalize =================
__global__ __launch_bounds__(256) void reduce_k(
    const float* __restrict__ pm1, const float* __restrict__ pm2,
    const int* __restrict__ pidx, int* __restrict__ fidx,
    float* __restrict__ outidxf, int* __restrict__ hist,
    unsigned long long* __restrict__ packed, int* __restrict__ list,
    int* __restrict__ flag, int* __restrict__ misc, float* __restrict__ sc1) {
  const int r = blockIdx.x * 256 + threadIdx.x;
  float m1 = 3e38f, m2 = 3e38f;
  int i1 = 0;
  for (int nb = 0; nb < NNB; ++nb) {   // ascending k: strict < keeps first
    const float om1 = pm1[(size_t)nb * NROW + r];
    const float om2 = pm2[(size_t)nb * NROW + r];
    const int oi1 = pidx[(size_t)nb * NROW + r];
    if (om1 < m1) { m2 = fminf(m1, om2); m1 = om1; i1 = oi1; }
    else          { m2 = fminf(m2, om1); }
  }
  fidx[r] = i1;
  outidxf[r] = (float)i1;
  sc1[r] = m1;                         // approx min score (for algebraic loss)
  atomicAdd(&hist[i1], 1);
  const int fl = (m2 - m1 < TAU) ? 1 : 0;
  flag[r] = fl;
  if (fl) {
    packed[r] = 0xFFFFFFFFFFFFFFFFull;
    const int p = atomicAdd(&misc[1], 1);
    list[p] = r;
  }
}

// ================= exact fp32 recompute (batched over flagged rows) =========
__global__ __launch_bounds__(256) void cleanup_k(
    const float* __restrict__ zt, const float* __restrict__ cb,
    const float* __restrict__ nrm, const int* __restrict__ list,
    const int* __restrict__ misc, unsigned long long* __restrict__ packed) {
  __shared__ float zr[16][256];
  __shared__ int lidx[16];
  __shared__ unsigned long long wred[16][4];
  const int tid = threadIdx.x;
  const int lane = tid & 63, wv = tid >> 6;
  const int nf = misc[1];
  const int k = blockIdx.x * 16 + (tid >> 4);
  const int cs1 = tid & 15;
  float creg[16];
#pragma unroll
  for (int j = 0; j < 16; ++j) creg[j] = cb[(size_t)k * 256 + cs1 + 16 * j];
  const float nk = nrm[k];

  for (int c0 = 0; c0 < nf; c0 += 16) {
    if (tid < 16) lidx[tid] = list[(c0 + tid < nf) ? (c0 + tid) : c0];
    __syncthreads();
#pragma unroll
    for (int j = 0; j < 16; ++j)
      zr[j][tid] = zt[(size_t)lidx[j] * 256 + tid];
    __syncthreads();
    const int rmax = (nf - c0 < 16) ? (nf - c0) : 16;
    for (int rr = 0; rr < rmax; ++rr) {
      float p = 0.f;
#pragma unroll
      for (int j = 0; j < 16; ++j) p += creg[j] * zr[rr][cs1 + 16 * j];
      p += __shfl_xor(p, 1); p += __shfl_xor(p, 2);
      p += __shfl_xor(p, 4); p += __shfl_xor(p, 8);
      unsigned long long v = 0xFFFFFFFFFFFFFFFFull;
      if (cs1 == 0) {
        const float s = nk - 2.f * p;
        unsigned u = __float_as_uint(s);
        u ^= (unsigned)((int)u >> 31) | 0x80000000u;   // sortable float
        v = ((unsigned long long)u << 32) | (unsigned)k;
      }
      {
        const unsigned long long o1 = __shfl_xor(v, 16);
        v = v < o1 ? v : o1;
        const unsigned long long o2 = __shfl_xor(v, 32);
        v = v < o2 ? v : o2;
      }
      if (lane == 0) wred[rr][wv] = v;
    }
    __syncthreads();
    if (tid < 16 && c0 + tid < nf) {
      unsigned long long b = wred[tid][0];
#pragma unroll
      for (int i = 1; i < 4; ++i) b = b < wred[tid][i] ? b : wred[tid][i];
      atomicMin(packed + lidx[tid], b);
    }
    __syncthreads();
  }
}

// ======== gather (blocks 0..4095) + fused final stats (block 4096) ==========
// final's inputs are all produced by dispatches <= cleanup, so it can ride in
// this dispatch as an extra block (saves one ~20us launch).
__global__ __launch_bounds__(256) void gather_k(
    const float* __restrict__ z, const float* __restrict__ cb,
    const int* __restrict__ idx, const int* __restrict__ flag,
    const unsigned long long* __restrict__ packed, float* __restrict__ out,
    const int* __restrict__ misc, const int* __restrict__ list,
    const int* __restrict__ hist, const float* __restrict__ sc1,
    const float* __restrict__ znp, float* __restrict__ outidxf,
    float* __restrict__ out_tail) {
  const int tid = threadIdx.x;
  if (blockIdx.x < 4096) {
    const int e = (blockIdx.x * 256 + tid) * 4;  // [b][c][hw], hw%4==0
    const int hw = e & 1023;
    const int bc = e >> 10;
    const int c = bc & 255;
    const int bimg = bc >> 8;
    const int n = (bimg << 10) + hw;
    int4 k4 = *(const int4*)(idx + n);
    const int4 f4 = *(const int4*)(flag + n);
    if (f4.x) k4.x = (int)(packed[n + 0] & 0xFFFFFFFFull);
    if (f4.y) k4.y = (int)(packed[n + 1] & 0xFFFFFFFFull);
    if (f4.z) k4.z = (int)(packed[n + 2] & 0xFFFFFFFFull);
    if (f4.w) k4.w = (int)(packed[n + 3] & 0xFFFFFFFFull);
    const float4 zv = *(const float4*)(z + e);
    const float q0 = cb[(size_t)k4.x * 256 + c];
    const float q1 = cb[(size_t)k4.y * 256 + c];
    const float q2 = cb[(size_t)k4.z * 256 + c];
    const float q3 = cb[(size_t)k4.w * 256 + c];
    float4 ov = {zv.x + (q0 - zv.x), zv.y + (q1 - zv.y),
                 zv.z + (q2 - zv.z), zv.w + (q3 - zv.w)};  // mirrors z+(q-z)
    *(float4*)(out + e) = ov;
  } else {
    // ---- final: idx fixups, delta-hist, perplexity, algebraic loss ----
    __shared__ int dh[KCB];           // 32 KB
    __shared__ float red[4];
    const int nf = misc[1];
    for (int k = tid; k < KCB; k += 256) dh[k] = 0;
    __syncthreads();
    float corr = 0.f;
    for (int f = tid; f < nf; f += 256) {
      const int r = list[f];
      const unsigned long long pk = packed[r];
      const int fin = (int)(pk & 0xFFFFFFFFull);
      const float ex = dec_sortable((unsigned)(pk >> 32));
      corr += ex - sc1[r];            // replace approx score with exact
      const int old = idx[r];
      if (fin != old) {
        atomicAdd(&dh[fin], 1);
        atomicSub(&dh[old], 1);
        outidxf[r] = (float)fin;
      }
    }
    __syncthreads();
    // perplexity over corrected hist
    float part = 0.f;
    for (int k = tid; k < KCB; k += 256) {
      const float p = (float)(hist[k] + dh[k]) * (1.0f / 16384.0f);
      part += p * logf(fmaxf(p, 1e-10f));
    }
    // loss = (sum ||z||^2 + sum_r s_r) / 4194304
    float ssum = 0.f;
    {
      const float* s4 = sc1 + tid * 64;
      for (int j = 0; j < 16; ++j) {
        const float4 v = *(const float4*)(s4 + 4 * j);
        ssum += v.x + v.y + v.z + v.w;
      }
      for (int i = tid; i < 1024; i += 256) ssum += znp[i];
      ssum += corr;
    }
    const int lane = tid & 63, wid = tid >> 6;
    for (int off = 32; off; off >>= 1) {
      part += __shfl_down(part, off);
      ssum += __shfl_down(ssum, off);
    }
    __shared__ float red2[4];
    if (lane == 0) { red[wid] = part; red2[wid] = ssum; }
    __syncthreads();
    if (tid == 0) {
      out_tail[0] = expf(-(red[0] + red[1] + red[2] + red[3]));  // perplexity
      const float mean =
          (red2[0] + red2[1] + red2[2] + red2[3]) * (1.0f / 4194304.0f);
      out_tail[1] = mean;                                        // loss_vq
      out_tail[2] = mean;                                        // loss_commit
    }
  }
}

extern "C" void kernel_launch(void* const* d_in, const int* in_sizes, int n_in,
                              void* d_out, int out_size, void* d_ws,
                              size_t ws_size, hipStream_t stream) {
  const float* z = (const float*)d_in[0];
  const float* cb = (const float*)d_in[1];
  float* out = (float*)d_out;
  char* ws = (char*)d_ws;

  unsigned long long* packed = (unsigned long long*)(ws + OFF_PACKED);
  unsigned short* A = (unsigned short*)(ws + OFF_A);
  unsigned short* B2 = (unsigned short*)(ws + OFF_B);
  float* zt = (float*)(ws + OFF_ZT);
  float* nrm = (float*)(ws + OFF_NRM);
  float* pm1 = (float*)(ws + OFF_PM1);
  float* pm2 = (float*)(ws + OFF_PM2);
  int* pidx = (int*)(ws + OFF_PIDX);
  int* fidx = (int*)(ws + OFF_FIDX);
  int* list = (int*)(ws + OFF_LIST);
  int* flag = (int*)(ws + OFF_FLAG);
  int* hist = (int*)(ws + OFF_HIST);
  int* misc = (int*)(ws + OFF_MISC);
  float* sc1 = (float*)(ws + OFF_SC1);
  float* znp = (float*)(ws + OFF_ZNP);
  float* outidxf = out + 4194304;
  float* out_tail = out + 4210688;

  prep_k<<<2592, 256, 0, stream>>>(z, cb, A, B2, zt, nrm, hist, misc, znp);
  vq_mfma_k<<<dim3(NNB, 128), 256, 0, stream>>>(A, B2, nrm, pm1, pm2, pidx);
  reduce_k<<<64, 256, 0, stream>>>(pm1, pm2, pidx, fidx, outidxf, hist, packed,
                                   list, flag, misc, sc1);
  cleanup_k<<<512, 256, 0, stream>>>(zt, cb, nrm, list, misc, packed);
  gather_k<<<4097, 256, 0, stream>>>(z, cb, fidx, flag, packed, out, misc,
                                     list, hist, sc1, znp, outidxf, out_tail);
}

// Round 10
// 720.155 us; speedup vs baseline: 1.1973x; 1.1973x over previous
//
#include <hip/hip_runtime.h>
#include <math.h>

typedef __attribute__((ext_vector_type(8))) __bf16 bf16x8;
typedef __attribute__((ext_vector_type(4))) float floatx4;

#define NROW 16384
#define KCB  8192
#define TAU  0.6f           // guard threshold (K=512 score err sigma~0.04-0.07)
#define NFCAP 1536          // flagged-row cap (expected ~900)
#define NNB  32             // KCB / 256 n-blocks

// workspace byte offsets (no overlays)
#define OFF_A      0u                    // 16384*512*2 = 16777216 (zh|zl)
#define OFF_B      16777216u             // 8192*256*2 = 4194304 frag-swizzled eh
#define OFF_ZT     20971520u             // 16384*256*4 fp32 z transposed
#define OFF_PM1    37748736u             // 32*16384*4
#define OFF_PM2    39845888u
#define OFF_PIDX   41943040u
#define OFF_NRM    44040192u             // 8192*4
#define OFF_FIDX   44072960u             // 16384*4
#define OFF_LIST   44138496u             // 16384*4
#define OFF_HIST   44204032u             // 8192*4
#define OFF_MISC   44236800u             // [0] corr f32, [1] cnt
#define OFF_SC1    44236816u             // 16384*4 approx min-score per row
#define OFF_ZNP    44302352u             // 1024*4 per-block ||z||^2 partials
#define OFF_PP     44306448u             // 1536*512*8 = 6291456 cleanup partials

__device__ __forceinline__ unsigned short f2bf(float f) {  // RNE fp32->bf16
  unsigned u = __float_as_uint(f);
  return (unsigned short)((u + 0x7FFFu + ((u >> 16) & 1u)) >> 16);
}
__device__ __forceinline__ float bf2f(unsigned short b) {
  return __uint_as_float(((unsigned)b) << 16);
}
__device__ __forceinline__ unsigned pack2(unsigned short a, unsigned short b) {
  return (unsigned)a | ((unsigned)b << 16);
}
__device__ __forceinline__ void gld16(const void* g, void* l) {
  __builtin_amdgcn_global_load_lds(
      (const __attribute__((address_space(1))) unsigned int*)g,
      (__attribute__((address_space(3))) unsigned int*)l, 16, 0, 0);
}
__device__ __forceinline__ float dec_sortable(unsigned u) {  // inverse encode
  return __uint_as_float((u & 0x80000000u) ? (u ^ 0x80000000u) : ~u);
}
__device__ __forceinline__ unsigned long long umin64(unsigned long long a,
                                                     unsigned long long b) {
  return a < b ? a : b;
}

// ================= fused prep =================
__global__ __launch_bounds__(256) void prep_k(
    const float* __restrict__ z, const float* __restrict__ cb,
    unsigned short* __restrict__ A, unsigned short* __restrict__ B2,
    float* __restrict__ zt, float* __restrict__ nrm, int* __restrict__ hist,
    int* __restrict__ misc, float* __restrict__ znp) {
  const int tid = threadIdx.x;
  if (blockIdx.x < 1024) {
    __shared__ float t[64][65];
    __shared__ float zps[4];
    const int bb = blockIdx.x >> 6;
    const int hw0 = ((blockIdx.x >> 2) & 15) * 64;
    const int c0 = (blockIdx.x & 3) * 64;
    const int cl = tid >> 2, h4 = (tid & 3) * 16;
    const float* src = z + ((size_t)(bb * 256 + c0 + cl)) * 1024 + hw0 + h4;
#pragma unroll
    for (int j = 0; j < 4; ++j) {
      const float4 v = *(const float4*)(src + 4 * j);
      t[cl][h4 + 4 * j + 0] = v.x; t[cl][h4 + 4 * j + 1] = v.y;
      t[cl][h4 + 4 * j + 2] = v.z; t[cl][h4 + 4 * j + 3] = v.w;
    }
    __syncthreads();
    const int hl = tid >> 2, cq = (tid & 3) * 16;
    const size_t n = (size_t)bb * 1024 + hw0 + hl;
    float fv[16];
    unsigned short hi[16], lo[16];
    float part = 0.f;
#pragma unroll
    for (int j = 0; j < 16; ++j) {
      const float f = t[cq + j][hl];
      fv[j] = f;
      part += f * f;
      const unsigned short h = f2bf(f);
      hi[j] = h;
      lo[j] = f2bf(f - bf2f(h));
    }
    unsigned short* dst = A + n * 512 + c0 + cq;
    uint4 h0 = {pack2(hi[0], hi[1]), pack2(hi[2], hi[3]), pack2(hi[4], hi[5]), pack2(hi[6], hi[7])};
    uint4 h1 = {pack2(hi[8], hi[9]), pack2(hi[10], hi[11]), pack2(hi[12], hi[13]), pack2(hi[14], hi[15])};
    uint4 l0 = {pack2(lo[0], lo[1]), pack2(lo[2], lo[3]), pack2(lo[4], lo[5]), pack2(lo[6], lo[7])};
    uint4 l1 = {pack2(lo[8], lo[9]), pack2(lo[10], lo[11]), pack2(lo[12], lo[13]), pack2(lo[14], lo[15])};
    *(uint4*)(dst) = h0;        *(uint4*)(dst + 8) = h1;       // zh at [c]
    *(uint4*)(dst + 256) = l0;  *(uint4*)(dst + 264) = l1;     // zl at [256+c]
    float* zp = zt + n * 256 + c0 + cq;
#pragma unroll
    for (int j = 0; j < 4; ++j) {
      float4 v = {fv[4 * j], fv[4 * j + 1], fv[4 * j + 2], fv[4 * j + 3]};
      *(float4*)(zp + 4 * j) = v;
    }
    const int lane = tid & 63, wid = tid >> 6;
    for (int off = 32; off; off >>= 1) part += __shfl_down(part, off);
    if (lane == 0) zps[wid] = part;
    __syncthreads();
    if (tid == 0) znp[blockIdx.x] = zps[0] + zps[1] + zps[2] + zps[3];
  } else if (blockIdx.x < 2048) {
    // one thread per B' octet: g = ((nb*8 + kk)*16 + ct)*64 + l
    const int g = (blockIdx.x - 1024) * 256 + tid;
    const int l = g & 63;
    const int ct = (g >> 6) & 15;
    const int kk = (g >> 10) & 7;
    const int nb = g >> 13;
    const int e = nb * 256 + ct * 16 + (l & 15);
    const int c0 = kk * 32 + (l >> 4) * 8;
    const float4 v0 = *(const float4*)(cb + (size_t)e * 256 + c0);
    const float4 v1 = *(const float4*)(cb + (size_t)e * 256 + c0 + 4);
    float f[8] = {v0.x, v0.y, v0.z, v0.w, v1.x, v1.y, v1.z, v1.w};
    unsigned short o[8];
#pragma unroll
    for (int j = 0; j < 8; ++j) o[j] = f2bf(f[j]);
    uint4 w = {pack2(o[0], o[1]), pack2(o[2], o[3]), pack2(o[4], o[5]), pack2(o[6], o[7])};
    *(uint4*)(B2 + (size_t)g * 8) = w;
  } else if (blockIdx.x < 2560) {
    const int row = (blockIdx.x - 2048) * 16 + (tid >> 4);
    const int l16 = tid & 15;
    const float* cr = cb + (size_t)row * 256 + l16 * 16;
    float s = 0.f;
#pragma unroll
    for (int j = 0; j < 4; ++j) {
      const float4 v = *(const float4*)(cr + 4 * j);
      s += v.x * v.x + v.y * v.y + v.z * v.z + v.w * v.w;
    }
    s += __shfl_xor(s, 8); s += __shfl_xor(s, 4);
    s += __shfl_xor(s, 2); s += __shfl_xor(s, 1);
    if (l16 == 0) nrm[row] = s;
  } else {
    const int i = blockIdx.x - 2560;   // 0..31
    hist[i * 256 + tid] = 0;
    if (i == 0 && tid < 2) misc[tid] = 0;
  }
}

// ================= main: bf16 MFMA distance GEMM + fused top-2 argmin ========
// K=512 split ([zh|zl].[eh|eh]); A in LDS (16 KB XOR-swizzle), B frags from
// pre-swizzled global (proven R8: ~170 us). terms: kc 0-3 zh.eh | 4-7 zl.eh
__global__ __launch_bounds__(256, 2) void vq_mfma_k(
    const unsigned short* __restrict__ A, const unsigned short* __restrict__ B2,
    const float* __restrict__ nrm, float* __restrict__ pm1,
    float* __restrict__ pm2, int* __restrict__ pidx) {
  __shared__ unsigned short As[128 * 64];  // 16 KB

  const int tid = threadIdx.x;
  const int mb = blockIdx.y, nb = blockIdx.x;
  const int w = tid >> 6, lane = tid & 63;
  const int quad = lane >> 4, lrow = lane & 15;

  const int sr = tid >> 3, ss = tid & 7;
  const int sq = ss ^ (sr & 7);
  const unsigned short* gA = A + (size_t)(mb * 128 + sr) * 512 + sq * 8;
  unsigned short* lA = As + sr * 64 + ss * 8;
  const unsigned short* bp =
      B2 + (size_t)nb * 65536 + (size_t)(w * 4) * 512 + lane * 8;

  floatx4 acc[8][4];
#pragma unroll
  for (int i = 0; i < 8; ++i)
#pragma unroll
    for (int j = 0; j < 4; ++j) acc[i][j] = (floatx4){0.f, 0.f, 0.f, 0.f};

  for (int kc = 0; kc < 8; ++kc) {
    const int koA = ((kc & 3) << 6) + ((kc >= 4) ? 256 : 0);
#pragma unroll
    for (int i = 0; i < 4; ++i)
      gld16(gA + (size_t)(i * 32) * 512 + koA, lA + i * 32 * 64);
    bf16x8 bfr[2][4];
#pragma unroll
    for (int ks = 0; ks < 2; ++ks) {
      const int phys = ((kc & 3) << 1) + ks;   // 0..7 (eh reused for zl pass)
#pragma unroll
      for (int nt = 0; nt < 4; ++nt)
        bfr[ks][nt] = *(const bf16x8*)(bp + (size_t)phys * 8192 + nt * 512);
    }
    __syncthreads();
#pragma unroll
    for (int ks = 0; ks < 2; ++ks) {
      bf16x8 af[8];
#pragma unroll
      for (int mt = 0; mt < 8; ++mt) {
        const int row = mt * 16 + lrow;
        const int slot = (ks * 4 + quad) ^ (row & 7);
        af[mt] = *(const bf16x8*)(As + row * 64 + slot * 8);
      }
#pragma unroll
      for (int mt = 0; mt < 8; ++mt)
#pragma unroll
        for (int nt = 0; nt < 4; ++nt)
          acc[mt][nt] = __builtin_amdgcn_mfma_f32_16x16x32_bf16(
              af[mt], bfr[ks][nt], acc[mt][nt], 0, 0, 0);
    }
    __syncthreads();
  }

  // ---- epilogue: score = nrm[k] - 2*dot; top-2 per row over 256 cols ----
  float nr[4];
#pragma unroll
  for (int nt = 0; nt < 4; ++nt) nr[nt] = nrm[nb * 256 + w * 64 + nt * 16 + lrow];

  float* Lm1 = (float*)As;             // overlay (As dead after loop)
  int* Li1 = (int*)(As + 2048);
  float* Lm2 = (float*)(As + 4096);
#pragma unroll
  for (int mt = 0; mt < 8; ++mt) {
#pragma unroll
    for (int p = 0; p < 4; ++p) {
      float m1 = 3e38f, m2 = 3e38f;
      int i1 = 0;
#pragma unroll
      for (int nt = 0; nt < 4; ++nt) {
        const float s = nr[nt] - 2.0f * acc[mt][nt][p];
        const int kg = nb * 256 + w * 64 + nt * 16 + lrow;
        if (s < m1) { m2 = m1; m1 = s; i1 = kg; }
        else m2 = fminf(m2, s);
      }
      for (int d = 1; d < 16; d <<= 1) {   // merge across 16 lrow lanes
        const float om1 = __shfl_xor(m1, d);
        const int oi1 = __shfl_xor(i1, d);
        const float om2 = __shfl_xor(m2, d);
        if (om1 < m1) { m2 = fminf(m1, om2); m1 = om1; i1 = oi1; }
        else          { m2 = fminf(m2, om1); }
      }
      if (lrow == 0) {
        const int rl = mt * 16 + quad * 4 + p;
        Lm1[rl * 4 + w] = m1; Li1[rl * 4 + w] = i1; Lm2[rl * 4 + w] = m2;
      }
    }
  }
  __syncthreads();
  if (tid < 128) {
    float m1 = Lm1[tid * 4], m2 = Lm2[tid * 4];
    int i1 = Li1[tid * 4];
#pragma unroll
    for (int v = 1; v < 4; ++v) {
      const float om1 = Lm1[tid * 4 + v], om2 = Lm2[tid * 4 + v];
      const int oi1 = Li1[tid * 4 + v];
      if (om1 < m1) { m2 = fminf(m1, om2); m1 = om1; i1 = oi1; }
      else          { m2 = fminf(m2, om1); }
    }
    const int r = mb * 128 + tid;
    pm1[(size_t)nb * NROW + r] = m1;
    pm2[(size_t)nb * NROW + r] = m2;
    pidx[(size_t)nb * NROW + r] = i1;
  }
}

// ================= reduce partials + provisional finalize =================
__global__ __launch_bounds__(256) void reduce_k(
    const float* __restrict__ pm1, const float* __restrict__ pm2,
    const int* __restrict__ pidx, int* __restrict__ fidx,
    float* __restrict__ outidxf, int* __restrict__ hist,
    int* __restrict__ list, int* __restrict__ misc, float* __restrict__ sc1) {
  const int r = blockIdx.x * 256 + threadIdx.x;
  float m1 = 3e38f, m2 = 3e38f;
  int i1 = 0;
  for (int nb = 0; nb < NNB; ++nb) {   // ascending k: strict < keeps first
    const float om1 = pm1[(size_t)nb * NROW + r];
    const float om2 = pm2[(size_t)nb * NROW + r];
    const int oi1 = pidx[(size_t)nb * NROW + r];
    if (om1 < m1) { m2 = fminf(m1, om2); m1 = om1; i1 = oi1; }
    else          { m2 = fminf(m2, om1); }
  }
  i1 &= 8191;                          // defensive clamp
  fidx[r] = i1;
  outidxf[r] = (float)i1;
  sc1[r] = m1;                         // approx min score (for algebraic loss)
  atomicAdd(&hist[i1], 1);
  if (m2 - m1 < TAU) {
    const int p = atomicAdd(&misc[1], 1);
    if (p < NFCAP) list[p] = r;
  }
}

// ======== cleanup phase 1: exact fp32 partial argmin, NO atomics ===========
// grid (512 kb x 4 rg): block owns 16 k (cb in regs) and a quarter of the
// flagged rows; per-row best written as plain u64 store to pp[f*512+kb].
__global__ __launch_bounds__(256) void cleanup_k(
    const float* __restrict__ zt, const float* __restrict__ cb,
    const float* __restrict__ nrm, const int* __restrict__ list,
    const int* __restrict__ misc, unsigned long long* __restrict__ pp) {
  __shared__ float zr[16][256];
  __shared__ int lidx[16];
  __shared__ unsigned long long wred[16][4];
  const int tid = threadIdx.x;
  const int lane = tid & 63, wv = tid >> 6;
  int nf = misc[1];
  if (nf > NFCAP) nf = NFCAP;
  if (nf < 0) nf = 0;
  const int kb = blockIdx.x;            // 0..511
  const int rg = blockIdx.y;            // 0..3
  const int rpr = (nf + 3) >> 2;
  const int f0 = rg * rpr;
  const int f1 = (f0 + rpr < nf) ? (f0 + rpr) : nf;
  const int k = kb * 16 + (tid >> 4);
  const int cs1 = tid & 15;
  float creg[16];
#pragma unroll
  for (int j = 0; j < 16; ++j) creg[j] = cb[(size_t)k * 256 + cs1 + 16 * j];
  const float nk = nrm[k];

  for (int c0 = f0; c0 < f1; c0 += 16) {
    if (tid < 16) lidx[tid] = list[(c0 + tid < f1) ? (c0 + tid) : c0] & 16383;
    __syncthreads();
#pragma unroll
    for (int j = 0; j < 16; ++j)
      zr[j][tid] = zt[(size_t)lidx[j] * 256 + tid];
    __syncthreads();
    const int rmax = (f1 - c0 < 16) ? (f1 - c0) : 16;
    for (int rr = 0; rr < rmax; ++rr) {
      float p = 0.f;
#pragma unroll
      for (int j = 0; j < 16; ++j) p += creg[j] * zr[rr][cs1 + 16 * j];
      p += __shfl_xor(p, 1); p += __shfl_xor(p, 2);
      p += __shfl_xor(p, 4); p += __shfl_xor(p, 8);
      unsigned long long v = 0xFFFFFFFFFFFFFFFFull;
      if (cs1 == 0) {
        const float s = nk - 2.f * p;
        unsigned u = __float_as_uint(s);
        u ^= (unsigned)((int)u >> 31) | 0x80000000u;   // sortable float
        v = ((unsigned long long)u << 32) | (unsigned)k;
      }
      v = umin64(v, __shfl_xor(v, 16));
      v = umin64(v, __shfl_xor(v, 32));
      if (lane == 0) wred[rr][wv] = v;
    }
    __syncthreads();
    if (tid < 16 && c0 + tid < f1) {
      unsigned long long b = wred[tid][0];
#pragma unroll
      for (int i = 1; i < 4; ++i) b = umin64(b, wred[tid][i]);
      pp[(size_t)(c0 + tid) * 512 + kb] = b;   // plain store, no contention
    }
    __syncthreads();
  }
}

// ======== cleanup phase 2: reduce 512 partials/row, write final idx ========
__global__ __launch_bounds__(256) void cleanup2_k(
    const unsigned long long* __restrict__ pp, const int* __restrict__ list,
    int* misc, int* __restrict__ fidx, float* __restrict__ outidxf,
    int* __restrict__ hist, const float* __restrict__ sc1) {
  __shared__ unsigned long long wr[4];
  const int tid = threadIdx.x;
  const int lane = tid & 63, wv = tid >> 6;
  int nf = misc[1];
  if (nf > NFCAP) nf = NFCAP;
  float corr = 0.f;
  for (int f = blockIdx.x; f < nf; f += 64) {
    const int r = list[f] & 16383;
    unsigned long long v = umin64(pp[(size_t)f * 512 + tid],
                                  pp[(size_t)f * 512 + 256 + tid]);
    v = umin64(v, __shfl_xor(v, 1));  v = umin64(v, __shfl_xor(v, 2));
    v = umin64(v, __shfl_xor(v, 4));  v = umin64(v, __shfl_xor(v, 8));
    v = umin64(v, __shfl_xor(v, 16)); v = umin64(v, __shfl_xor(v, 32));
    if (lane == 0) wr[wv] = v;
    __syncthreads();
    if (tid == 0) {
      unsigned long long b = umin64(umin64(wr[0], wr[1]), umin64(wr[2], wr[3]));
      const int fin = (int)(b & 0xFFFFFFFFull) & 8191;   // defensive clamp
      corr += dec_sortable((unsigned)(b >> 32)) - sc1[r];
      const int old = fidx[r] & 8191;
      if (fin != old) {
        fidx[r] = fin;                 // plain write; gather is next dispatch
        outidxf[r] = (float)fin;
        atomicAdd(&hist[fin], 1);
        atomicSub(&hist[old], 1);
      }
    }
    __syncthreads();
  }
  if (tid == 0) atomicAdd((float*)&misc[0], corr);
}

// ======== gather (blocks 0..4095) + fused final stats (block 4096) ==========
__global__ __launch_bounds__(256) void gather_k(
    const float* __restrict__ z, const float* __restrict__ cb,
    const int* __restrict__ idx, float* __restrict__ out,
    const int* __restrict__ misc, const int* __restrict__ hist,
    const float* __restrict__ sc1, const float* __restrict__ znp,
    float* __restrict__ out_tail) {
  const int tid = threadIdx.x;
  if (blockIdx.x < 4096) {
    const int e = (blockIdx.x * 256 + tid) * 4;  // [b][c][hw], hw%4==0
    const int hw = e & 1023;
    const int bc = e >> 10;
    const int c = bc & 255;
    const int bimg = bc >> 8;
    const int n = (bimg << 10) + hw;
    int4 k4 = *(const int4*)(idx + n);           // idx already final
    k4.x &= 8191; k4.y &= 8191; k4.z &= 8191; k4.w &= 8191;  // defensive
    const float4 zv = *(const float4*)(z + e);
    const float q0 = cb[(size_t)k4.x * 256 + c];
    const float q1 = cb[(size_t)k4.y * 256 + c];
    const float q2 = cb[(size_t)k4.z * 256 + c];
    const float q3 = cb[(size_t)k4.w * 256 + c];
    float4 ov = {zv.x + (q0 - zv.x), zv.y + (q1 - zv.y),
                 zv.z + (q2 - zv.z), zv.w + (q3 - zv.w)};  // mirrors z+(q-z)
    *(float4*)(out + e) = ov;
  } else {
    // ---- final stats: perplexity (hist already corrected) + algebraic loss
    __shared__ float red[4], red2[4];
    float part = 0.f;
    for (int k = tid; k < KCB; k += 256) {
      const float p = (float)hist[k] * (1.0f / 16384.0f);
      part += p * logf(fmaxf(p, 1e-10f));
    }
    // loss = (sum ||z||^2 + sum_r s_r(approx) + corr) / 4194304
    float ssum = 0.f;
    const float* s4 = sc1 + tid * 64;
    for (int j = 0; j < 16; ++j) {
      const float4 v = *(const float4*)(s4 + 4 * j);
      ssum += v.x + v.y + v.z + v.w;
    }
    for (int i = tid; i < 1024; i += 256) ssum += znp[i];
    if (tid == 0) ssum += ((const float*)misc)[0];    // corr
    const int lane = tid & 63, wid = tid >> 6;
    for (int off = 32; off; off >>= 1) {
      part += __shfl_down(part, off);
      ssum += __shfl_down(ssum, off);
    }
    if (lane == 0) { red[wid] = part; red2[wid] = ssum; }
    __syncthreads();
    if (tid == 0) {
      out_tail[0] = expf(-(red[0] + red[1] + red[2] + red[3]));  // perplexity
      const float mean =
          (red2[0] + red2[1] + red2[2] + red2[3]) * (1.0f / 4194304.0f);
      out_tail[1] = mean;                                        // loss_vq
      out_tail[2] = mean;                                        // loss_commit
    }
  }
}

extern "C" void kernel_launch(void* const* d_in, const int* in_sizes, int n_in,
                              void* d_out, int out_size, void* d_ws,
                              size_t ws_size, hipStream_t stream) {
  const float* z = (const float*)d_in[0];
  const float* cb = (const float*)d_in[1];
  float* out = (float*)d_out;
  char* ws = (char*)d_ws;

  unsigned short* A = (unsigned short*)(ws + OFF_A);
  unsigned short* B2 = (unsigned short*)(ws + OFF_B);
  float* zt = (float*)(ws + OFF_ZT);
  float* nrm = (float*)(ws + OFF_NRM);
  float* pm1 = (float*)(ws + OFF_PM1);
  float* pm2 = (float*)(ws + OFF_PM2);
  int* pidx = (int*)(ws + OFF_PIDX);
  unsigned long long* pp = (unsigned long long*)(ws + OFF_PP);
  int* fidx = (int*)(ws + OFF_FIDX);
  int* list = (int*)(ws + OFF_LIST);
  int* hist = (int*)(ws + OFF_HIST);
  int* misc = (int*)(ws + OFF_MISC);
  float* sc1 = (float*)(ws + OFF_SC1);
  float* znp = (float*)(ws + OFF_ZNP);
  float* outidxf = out + 4194304;
  float* out_tail = out + 4210688;

  prep_k<<<2592, 256, 0, stream>>>(z, cb, A, B2, zt, nrm, hist, misc, znp);
  vq_mfma_k<<<dim3(NNB, 128), 256, 0, stream>>>(A, B2, nrm, pm1, pm2, pidx);
  reduce_k<<<64, 256, 0, stream>>>(pm1, pm2, pidx, fidx, outidxf, hist, list,
                                   misc, sc1);
  cleanup_k<<<dim3(512, 4), 256, 0, stream>>>(zt, cb, nrm, list, misc, pp);
  cleanup2_k<<<64, 256, 0, stream>>>(pp, list, misc, fidx, outidxf, hist, sc1);
  gather_k<<<4097, 256, 0, stream>>>(z, cb, fidx, out, misc, hist, sc1, znp,
                                     out_tail);
}

// Round 11
// 391.633 us; speedup vs baseline: 2.2017x; 1.8389x over previous
//
#include <hip/hip_runtime.h>
#include <math.h>

typedef __attribute__((ext_vector_type(8))) __bf16 bf16x8;
typedef __attribute__((ext_vector_type(4))) float floatx4;

#define NROW 16384
#define KCB  8192
#define TAU  0.05f          // guard threshold; K=768 3-term err sigma ~5e-4 -> 100 sigma
#define NFCAP 512           // flagged-row cap (expected ~91)
#define NNB  32             // KCB / 256 n-blocks

// workspace byte offsets (no overlays)
#define OFF_A      0u                    // 16384*512*2 = 16777216 (zh|zl)
#define OFF_B      16777216u             // 8192*512*2 = 8388608 frag-swizzled [eh|el]
#define OFF_ZT     25165824u             // 16384*256*4 fp32 z transposed
#define OFF_PM1    41943040u             // 32*16384*4
#define OFF_PM2    44040192u
#define OFF_PIDX   46137344u
#define OFF_NRM    48234496u             // 8192*4
#define OFF_FIDX   48267264u             // 16384*4
#define OFF_LIST   48332800u             // 16384*4
#define OFF_HIST   48398336u             // 8192*4
#define OFF_MISC   48431104u             // [0] corr f32, [1] cnt
#define OFF_SC1    48431120u             // 16384*4 approx min-score per row
#define OFF_ZNP    48496656u             // 1024*4 per-block ||z||^2 partials
#define OFF_PP     48500752u             // 512*512*8 = 2097152 cleanup partials

__device__ __forceinline__ unsigned short f2bf(float f) {  // RNE fp32->bf16
  unsigned u = __float_as_uint(f);
  return (unsigned short)((u + 0x7FFFu + ((u >> 16) & 1u)) >> 16);
}
__device__ __forceinline__ float bf2f(unsigned short b) {
  return __uint_as_float(((unsigned)b) << 16);
}
__device__ __forceinline__ unsigned pack2(unsigned short a, unsigned short b) {
  return (unsigned)a | ((unsigned)b << 16);
}
__device__ __forceinline__ void gld16(const void* g, void* l) {
  __builtin_amdgcn_global_load_lds(
      (const __attribute__((address_space(1))) unsigned int*)g,
      (__attribute__((address_space(3))) unsigned int*)l, 16, 0, 0);
}
__device__ __forceinline__ float dec_sortable(unsigned u) {  // inverse encode
  return __uint_as_float((u & 0x80000000u) ? (u ^ 0x80000000u) : ~u);
}
__device__ __forceinline__ unsigned long long umin64(unsigned long long a,
                                                     unsigned long long b) {
  return a < b ? a : b;
}

// ================= fused prep =================
// bid <1024:      A-prep (z transpose -> A'[n][512]=[zh|zl] + zt fp32 + znp)
// 1024..3071:     B'-prep: frag-swizzled, 16 phys slots: 0-7 eh, 8-15 el
// 3072..3583:     codebook norms (16 rows/block)
// 3584..3615:     zero hist (+ misc on first)
__global__ __launch_bounds__(256) void prep_k(
    const float* __restrict__ z, const float* __restrict__ cb,
    unsigned short* __restrict__ A, unsigned short* __restrict__ B2,
    float* __restrict__ zt, float* __restrict__ nrm, int* __restrict__ hist,
    int* __restrict__ misc, float* __restrict__ znp) {
  const int tid = threadIdx.x;
  if (blockIdx.x < 1024) {
    __shared__ float t[64][65];
    __shared__ float zps[4];
    const int bb = blockIdx.x >> 6;
    const int hw0 = ((blockIdx.x >> 2) & 15) * 64;
    const int c0 = (blockIdx.x & 3) * 64;
    const int cl = tid >> 2, h4 = (tid & 3) * 16;
    const float* src = z + ((size_t)(bb * 256 + c0 + cl)) * 1024 + hw0 + h4;
#pragma unroll
    for (int j = 0; j < 4; ++j) {
      const float4 v = *(const float4*)(src + 4 * j);
      t[cl][h4 + 4 * j + 0] = v.x; t[cl][h4 + 4 * j + 1] = v.y;
      t[cl][h4 + 4 * j + 2] = v.z; t[cl][h4 + 4 * j + 3] = v.w;
    }
    __syncthreads();
    const int hl = tid >> 2, cq = (tid & 3) * 16;
    const size_t n = (size_t)bb * 1024 + hw0 + hl;
    float fv[16];
    unsigned short hi[16], lo[16];
    float part = 0.f;
#pragma unroll
    for (int j = 0; j < 16; ++j) {
      const float f = t[cq + j][hl];
      fv[j] = f;
      part += f * f;
      const unsigned short h = f2bf(f);
      hi[j] = h;
      lo[j] = f2bf(f - bf2f(h));
    }
    unsigned short* dst = A + n * 512 + c0 + cq;
    uint4 h0 = {pack2(hi[0], hi[1]), pack2(hi[2], hi[3]), pack2(hi[4], hi[5]), pack2(hi[6], hi[7])};
    uint4 h1 = {pack2(hi[8], hi[9]), pack2(hi[10], hi[11]), pack2(hi[12], hi[13]), pack2(hi[14], hi[15])};
    uint4 l0 = {pack2(lo[0], lo[1]), pack2(lo[2], lo[3]), pack2(lo[4], lo[5]), pack2(lo[6], lo[7])};
    uint4 l1 = {pack2(lo[8], lo[9]), pack2(lo[10], lo[11]), pack2(lo[12], lo[13]), pack2(lo[14], lo[15])};
    *(uint4*)(dst) = h0;        *(uint4*)(dst + 8) = h1;       // zh at [c]
    *(uint4*)(dst + 256) = l0;  *(uint4*)(dst + 264) = l1;     // zl at [256+c]
    float* zp = zt + n * 256 + c0 + cq;
#pragma unroll
    for (int j = 0; j < 4; ++j) {
      float4 v = {fv[4 * j], fv[4 * j + 1], fv[4 * j + 2], fv[4 * j + 3]};
      *(float4*)(zp + 4 * j) = v;
    }
    const int lane = tid & 63, wid = tid >> 6;
    for (int off = 32; off; off >>= 1) part += __shfl_down(part, off);
    if (lane == 0) zps[wid] = part;
    __syncthreads();
    if (tid == 0) znp[blockIdx.x] = zps[0] + zps[1] + zps[2] + zps[3];
  } else if (blockIdx.x < 3072) {
    // one thread per B' octet: g = ((nb*16 + phys)*16 + ct)*64 + l
    const int g = (blockIdx.x - 1024) * 256 + tid;
    const int l = g & 63;
    const int ct = (g >> 6) & 15;
    const int phys = (g >> 10) & 15;
    const int nb = g >> 14;
    const int e = nb * 256 + ct * 16 + (l & 15);
    const int c0 = (phys & 7) * 32 + (l >> 4) * 8;
    const float4 v0 = *(const float4*)(cb + (size_t)e * 256 + c0);
    const float4 v1 = *(const float4*)(cb + (size_t)e * 256 + c0 + 4);
    float f[8] = {v0.x, v0.y, v0.z, v0.w, v1.x, v1.y, v1.z, v1.w};
    unsigned short o[8];
    if (phys < 8) {
#pragma unroll
      for (int j = 0; j < 8; ++j) o[j] = f2bf(f[j]);          // eh
    } else {
#pragma unroll
      for (int j = 0; j < 8; ++j) {
        const unsigned short h = f2bf(f[j]);
        o[j] = f2bf(f[j] - bf2f(h));                          // el
      }
    }
    uint4 w = {pack2(o[0], o[1]), pack2(o[2], o[3]), pack2(o[4], o[5]), pack2(o[6], o[7])};
    *(uint4*)(B2 + (size_t)g * 8) = w;
  } else if (blockIdx.x < 3584) {
    const int row = (blockIdx.x - 3072) * 16 + (tid >> 4);
    const int l16 = tid & 15;
    const float* cr = cb + (size_t)row * 256 + l16 * 16;
    float s = 0.f;
#pragma unroll
    for (int j = 0; j < 4; ++j) {
      const float4 v = *(const float4*)(cr + 4 * j);
      s += v.x * v.x + v.y * v.y + v.z * v.z + v.w * v.w;
    }
    s += __shfl_xor(s, 8); s += __shfl_xor(s, 4);
    s += __shfl_xor(s, 2); s += __shfl_xor(s, 1);
    if (l16 == 0) nrm[row] = s;
  } else {
    const int i = blockIdx.x - 3584;   // 0..31
    hist[i * 256 + tid] = 0;
    if (i == 0 && tid < 2) misc[tid] = 0;
  }
}

// ================= main: bf16 MFMA distance GEMM + fused top-2 argmin ========
// K=768 3-term ([zh|zh|zl].[eh|el|eh]); A in LDS (16 KB XOR-swizzle), B frags
// from pre-swizzled global (R8/R10 structure). terms:
//   kc 0-3: zh.eh | kc 4-7: zh.el | kc 8-11: zl.eh
__global__ __launch_bounds__(256, 2) void vq_mfma_k(
    const unsigned short* __restrict__ A, const unsigned short* __restrict__ B2,
    const float* __restrict__ nrm, float* __restrict__ pm1,
    float* __restrict__ pm2, int* __restrict__ pidx) {
  __shared__ unsigned short As[128 * 64];  // 16 KB

  const int tid = threadIdx.x;
  const int mb = blockIdx.y, nb = blockIdx.x;
  const int w = tid >> 6, lane = tid & 63;
  const int quad = lane >> 4, lrow = lane & 15;

  const int sr = tid >> 3, ss = tid & 7;
  const int sq = ss ^ (sr & 7);
  const unsigned short* gA = A + (size_t)(mb * 128 + sr) * 512 + sq * 8;
  unsigned short* lA = As + sr * 64 + ss * 8;
  const unsigned short* bp =
      B2 + (size_t)nb * 131072 + (size_t)(w * 4) * 512 + lane * 8;

  floatx4 acc[8][4];
#pragma unroll
  for (int i = 0; i < 8; ++i)
#pragma unroll
    for (int j = 0; j < 4; ++j) acc[i][j] = (floatx4){0.f, 0.f, 0.f, 0.f};

  for (int kc = 0; kc < 12; ++kc) {
    // A chunk: zh for kc 0-7 (same data twice), zl for kc 8-11
    const int koA = ((kc & 3) << 6) + ((kc >= 8) ? 256 : 0);
#pragma unroll
    for (int i = 0; i < 4; ++i)
      gld16(gA + (size_t)(i * 32) * 512 + koA, lA + i * 32 * 64);
    bf16x8 bfr[2][4];
#pragma unroll
    for (int ks = 0; ks < 2; ++ks) {
      // B phys slot: eh(0-7) for terms 1,3; el(8-15) for term 2
      const int base = (kc >= 4 && kc < 8) ? 8 : 0;
      const int phys = base + ((kc & 3) << 1) + ks;
#pragma unroll
      for (int nt = 0; nt < 4; ++nt)
        bfr[ks][nt] = *(const bf16x8*)(bp + (size_t)phys * 8192 + nt * 512);
    }
    __syncthreads();
#pragma unroll
    for (int ks = 0; ks < 2; ++ks) {
      bf16x8 af[8];
#pragma unroll
      for (int mt = 0; mt < 8; ++mt) {
        const int row = mt * 16 + lrow;
        const int slot = (ks * 4 + quad) ^ (row & 7);
        af[mt] = *(const bf16x8*)(As + row * 64 + slot * 8);
      }
#pragma unroll
      for (int mt = 0; mt < 8; ++mt)
#pragma unroll
        for (int nt = 0; nt < 4; ++nt)
          acc[mt][nt] = __builtin_amdgcn_mfma_f32_16x16x32_bf16(
              af[mt], bfr[ks][nt], acc[mt][nt], 0, 0, 0);
    }
    __syncthreads();
  }

  // ---- epilogue: score = nrm[k] - 2*dot; top-2 per row over 256 cols ----
  float nr[4];
#pragma unroll
  for (int nt = 0; nt < 4; ++nt) nr[nt] = nrm[nb * 256 + w * 64 + nt * 16 + lrow];

  float* Lm1 = (float*)As;             // overlay (As dead after loop)
  int* Li1 = (int*)(As + 2048);
  float* Lm2 = (float*)(As + 4096);
#pragma unroll
  for (int mt = 0; mt < 8; ++mt) {
#pragma unroll
    for (int p = 0; p < 4; ++p) {
      float m1 = 3e38f, m2 = 3e38f;
      int i1 = 0;
#pragma unroll
      for (int nt = 0; nt < 4; ++nt) {
        const float s = nr[nt] - 2.0f * acc[mt][nt][p];
        const int kg = nb * 256 + w * 64 + nt * 16 + lrow;
        if (s < m1) { m2 = m1; m1 = s; i1 = kg; }
        else m2 = fminf(m2, s);
      }
      for (int d = 1; d < 16; d <<= 1) {   // merge across 16 lrow lanes
        const float om1 = __shfl_xor(m1, d);
        const int oi1 = __shfl_xor(i1, d);
        const float om2 = __shfl_xor(m2, d);
        if (om1 < m1) { m2 = fminf(m1, om2); m1 = om1; i1 = oi1; }
        else          { m2 = fminf(m2, om1); }
      }
      if (lrow == 0) {
        const int rl = mt * 16 + quad * 4 + p;
        Lm1[rl * 4 + w] = m1; Li1[rl * 4 + w] = i1; Lm2[rl * 4 + w] = m2;
      }
    }
  }
  __syncthreads();
  if (tid < 128) {
    float m1 = Lm1[tid * 4], m2 = Lm2[tid * 4];
    int i1 = Li1[tid * 4];
#pragma unroll
    for (int v = 1; v < 4; ++v) {
      const float om1 = Lm1[tid * 4 + v], om2 = Lm2[tid * 4 + v];
      const int oi1 = Li1[tid * 4 + v];
      if (om1 < m1) { m2 = fminf(m1, om2); m1 = om1; i1 = oi1; }
      else          { m2 = fminf(m2, om1); }
    }
    const int r = mb * 128 + tid;
    pm1[(size_t)nb * NROW + r] = m1;
    pm2[(size_t)nb * NROW + r] = m2;
    pidx[(size_t)nb * NROW + r] = i1;
  }
}

// ================= reduce partials + provisional finalize =================
__global__ __launch_bounds__(256) void reduce_k(
    const float* __restrict__ pm1, const float* __restrict__ pm2,
    const int* __restrict__ pidx, int* __restrict__ fidx,
    float* __restrict__ outidxf, int* __restrict__ hist,
    int* __restrict__ list, int* __restrict__ misc, float* __restrict__ sc1) {
  const int r = blockIdx.x * 256 + threadIdx.x;
  float m1 = 3e38f, m2 = 3e38f;
  int i1 = 0;
  for (int nb = 0; nb < NNB; ++nb) {   // ascending k: strict < keeps first
    const float om1 = pm1[(size_t)nb * NROW + r];
    const float om2 = pm2[(size_t)nb * NROW + r];
    const int oi1 = pidx[(size_t)nb * NROW + r];
    if (om1 < m1) { m2 = fminf(m1, om2); m1 = om1; i1 = oi1; }
    else          { m2 = fminf(m2, om1); }
  }
  i1 &= 8191;                          // defensive clamp
  fidx[r] = i1;
  outidxf[r] = (float)i1;
  sc1[r] = m1;                         // approx min score (for algebraic loss)
  atomicAdd(&hist[i1], 1);
  if (m2 - m1 < TAU) {
    const int p = atomicAdd(&misc[1], 1);
    if (p < NFCAP) list[p] = r;
  }
}

// ======== cleanup phase 1: exact fp32 partial argmin, NO atomics ===========
// grid (512 kb x 4 rg): block owns 16 k (cb in regs) and a quarter of the
// flagged rows; per-row best written as plain u64 store to pp[f*512+kb].
// (R10 lesson: this kernel is DS-issue bound, linear in nf — kept identical;
//  the fix was upstream: 3-term split -> nf ~91 not ~900.)
__global__ __launch_bounds__(256) void cleanup_k(
    const float* __restrict__ zt, const float* __restrict__ cb,
    const float* __restrict__ nrm, const int* __restrict__ list,
    const int* __restrict__ misc, unsigned long long* __restrict__ pp) {
  __shared__ float zr[16][256];
  __shared__ int lidx[16];
  __shared__ unsigned long long wred[16][4];
  const int tid = threadIdx.x;
  const int lane = tid & 63, wv = tid >> 6;
  int nf = misc[1];
  if (nf > NFCAP) nf = NFCAP;
  if (nf < 0) nf = 0;
  const int kb = blockIdx.x;            // 0..511
  const int rg = blockIdx.y;            // 0..3
  const int rpr = (nf + 3) >> 2;
  const int f0 = rg * rpr;
  const int f1 = (f0 + rpr < nf) ? (f0 + rpr) : nf;
  const int k = kb * 16 + (tid >> 4);
  const int cs1 = tid & 15;
  float creg[16];
#pragma unroll
  for (int j = 0; j < 16; ++j) creg[j] = cb[(size_t)k * 256 + cs1 + 16 * j];
  const float nk = nrm[k];

  for (int c0 = f0; c0 < f1; c0 += 16) {
    if (tid < 16) lidx[tid] = list[(c0 + tid < f1) ? (c0 + tid) : c0] & 16383;
    __syncthreads();
#pragma unroll
    for (int j = 0; j < 16; ++j)
      zr[j][tid] = zt[(size_t)lidx[j] * 256 + tid];
    __syncthreads();
    const int rmax = (f1 - c0 < 16) ? (f1 - c0) : 16;
    for (int rr = 0; rr < rmax; ++rr) {
      float p = 0.f;
#pragma unroll
      for (int j = 0; j < 16; ++j) p += creg[j] * zr[rr][cs1 + 16 * j];
      p += __shfl_xor(p, 1); p += __shfl_xor(p, 2);
      p += __shfl_xor(p, 4); p += __shfl_xor(p, 8);
      unsigned long long v = 0xFFFFFFFFFFFFFFFFull;
      if (cs1 == 0) {
        const float s = nk - 2.f * p;
        unsigned u = __float_as_uint(s);
        u ^= (unsigned)((int)u >> 31) | 0x80000000u;   // sortable float
        v = ((unsigned long long)u << 32) | (unsigned)k;
      }
      v = umin64(v, __shfl_xor(v, 16));
      v = umin64(v, __shfl_xor(v, 32));
      if (lane == 0) wred[rr][wv] = v;
    }
    __syncthreads();
    if (tid < 16 && c0 + tid < f1) {
      unsigned long long b = wred[tid][0];
#pragma unroll
      for (int i = 1; i < 4; ++i) b = umin64(b, wred[tid][i]);
      pp[(size_t)(c0 + tid) * 512 + kb] = b;   // plain store, no contention
    }
    __syncthreads();
  }
}

// ======== cleanup phase 2: reduce 512 partials/row, write final idx ========
__global__ __launch_bounds__(256) void cleanup2_k(
    const unsigned long long* __restrict__ pp, const int* __restrict__ list,
    int* misc, int* __restrict__ fidx, float* __restrict__ outidxf,
    int* __restrict__ hist, const float* __restrict__ sc1) {
  __shared__ unsigned long long wr[4];
  const int tid = threadIdx.x;
  const int lane = tid & 63, wv = tid >> 6;
  int nf = misc[1];
  if (nf > NFCAP) nf = NFCAP;
  float corr = 0.f;
  for (int f = blockIdx.x; f < nf; f += 64) {
    const int r = list[f] & 16383;
    unsigned long long v = umin64(pp[(size_t)f * 512 + tid],
                                  pp[(size_t)f * 512 + 256 + tid]);
    v = umin64(v, __shfl_xor(v, 1));  v = umin64(v, __shfl_xor(v, 2));
    v = umin64(v, __shfl_xor(v, 4));  v = umin64(v, __shfl_xor(v, 8));
    v = umin64(v, __shfl_xor(v, 16)); v = umin64(v, __shfl_xor(v, 32));
    if (lane == 0) wr[wv] = v;
    __syncthreads();
    if (tid == 0) {
      unsigned long long b = umin64(umin64(wr[0], wr[1]), umin64(wr[2], wr[3]));
      const int fin = (int)(b & 0xFFFFFFFFull) & 8191;   // defensive clamp
      corr += dec_sortable((unsigned)(b >> 32)) - sc1[r];
      const int old = fidx[r] & 8191;
      if (fin != old) {
        fidx[r] = fin;                 // plain write; gather is next dispatch
        outidxf[r] = (float)fin;
        atomicAdd(&hist[fin], 1);
        atomicSub(&hist[old], 1);
      }
    }
    __syncthreads();
  }
  if (tid == 0) atomicAdd((float*)&misc[0], corr);
}

// ======== gather (blocks 0..4095) + fused final stats (block 4096) ==========
__global__ __launch_bounds__(256) void gather_k(
    const float* __restrict__ z, const float* __restrict__ cb,
    const int* __restrict__ idx, float* __restrict__ out,
    const int* __restrict__ misc, const int* __restrict__ hist,
    const float* __restrict__ sc1, const float* __restrict__ znp,
    float* __restrict__ out_tail) {
  const int tid = threadIdx.x;
  if (blockIdx.x < 4096) {
    const int e = (blockIdx.x * 256 + tid) * 4;  // [b][c][hw], hw%4==0
    const int hw = e & 1023;
    const int bc = e >> 10;
    const int c = bc & 255;
    const int bimg = bc >> 8;
    const int n = (bimg << 10) + hw;
    int4 k4 = *(const int4*)(idx + n);           // idx already final
    k4.x &= 8191; k4.y &= 8191; k4.z &= 8191; k4.w &= 8191;  // defensive
    const float4 zv = *(const float4*)(z + e);
    const float q0 = cb[(size_t)k4.x * 256 + c];
    const float q1 = cb[(size_t)k4.y * 256 + c];
    const float q2 = cb[(size_t)k4.z * 256 + c];
    const float q3 = cb[(size_t)k4.w * 256 + c];
    float4 ov = {zv.x + (q0 - zv.x), zv.y + (q1 - zv.y),
                 zv.z + (q2 - zv.z), zv.w + (q3 - zv.w)};  // mirrors z+(q-z)
    *(float4*)(out + e) = ov;
  } else {
    // ---- final stats: perplexity (hist already corrected) + algebraic loss
    __shared__ float red[4], red2[4];
    float part = 0.f;
    for (int k = tid; k < KCB; k += 256) {
      const float p = (float)hist[k] * (1.0f / 16384.0f);
      part += p * logf(fmaxf(p, 1e-10f));
    }
    // loss = (sum ||z||^2 + sum_r s_r(approx) + corr) / 4194304
    float ssum = 0.f;
    const float* s4 = sc1 + tid * 64;
    for (int j = 0; j < 16; ++j) {
      const float4 v = *(const float4*)(s4 + 4 * j);
      ssum += v.x + v.y + v.z + v.w;
    }
    for (int i = tid; i < 1024; i += 256) ssum += znp[i];
    if (tid == 0) ssum += ((const float*)misc)[0];    // corr
    const int lane = tid & 63, wid = tid >> 6;
    for (int off = 32; off; off >>= 1) {
      part += __shfl_down(part, off);
      ssum += __shfl_down(ssum, off);
    }
    if (lane == 0) { red[wid] = part; red2[wid] = ssum; }
    __syncthreads();
    if (tid == 0) {
      out_tail[0] = expf(-(red[0] + red[1] + red[2] + red[3]));  // perplexity
      const float mean =
          (red2[0] + red2[1] + red2[2] + red2[3]) * (1.0f / 4194304.0f);
      out_tail[1] = mean;                                        // loss_vq
      out_tail[2] = mean;                                        // loss_commit
    }
  }
}

extern "C" void kernel_launch(void* const* d_in, const int* in_sizes, int n_in,
                              void* d_out, int out_size, void* d_ws,
                              size_t ws_size, hipStream_t stream) {
  const float* z = (const float*)d_in[0];
  const float* cb = (const float*)d_in[1];
  float* out = (float*)d_out;
  char* ws = (char*)d_ws;

  unsigned short* A = (unsigned short*)(ws + OFF_A);
  unsigned short* B2 = (unsigned short*)(ws + OFF_B);
  float* zt = (float*)(ws + OFF_ZT);
  float* nrm = (float*)(ws + OFF_NRM);
  float* pm1 = (float*)(ws + OFF_PM1);
  float* pm2 = (float*)(ws + OFF_PM2);
  int* pidx = (int*)(ws + OFF_PIDX);
  unsigned long long* pp = (unsigned long long*)(ws + OFF_PP);
  int* fidx = (int*)(ws + OFF_FIDX);
  int* list = (int*)(ws + OFF_LIST);
  int* hist = (int*)(ws + OFF_HIST);
  int* misc = (int*)(ws + OFF_MISC);
  float* sc1 = (float*)(ws + OFF_SC1);
  float* znp = (float*)(ws + OFF_ZNP);
  float* outidxf = out + 4194304;
  float* out_tail = out + 4210688;

  prep_k<<<3616, 256, 0, stream>>>(z, cb, A, B2, zt, nrm, hist, misc, znp);
  vq_mfma_k<<<dim3(NNB, 128), 256, 0, stream>>>(A, B2, nrm, pm1, pm2, pidx);
  reduce_k<<<64, 256, 0, stream>>>(pm1, pm2, pidx, fidx, outidxf, hist, list,
                                   misc, sc1);
  cleanup_k<<<dim3(512, 4), 256, 0, stream>>>(zt, cb, nrm, list, misc, pp);
  cleanup2_k<<<64, 256, 0, stream>>>(pp, list, misc, fidx, outidxf, hist, sc1);
  gather_k<<<4097, 256, 0, stream>>>(z, cb, fidx, out, misc, hist, sc1, znp,
                                     out_tail);
}